// Round 7
// baseline (969.956 us; speedup 1.0000x reference)
//
#include <hip/hip_runtime.h>

using u16 = unsigned short;
using u32 = unsigned int;

typedef short bf16x8 __attribute__((ext_vector_type(8)));
typedef float f32x4 __attribute__((ext_vector_type(4)));

__device__ __forceinline__ float b2f(u16 u) { return __uint_as_float(((u32)u) << 16); }
__device__ __forceinline__ u16 f2bf(float f) {
  u32 u = __float_as_uint(f);
  u32 r = (u + 0x7fffu + ((u >> 16) & 1u)) >> 16;
  return (u16)r;
}
__device__ __forceinline__ u16 f2bf_trunc(float f) {  // cheap truncate (P probs only)
  return (u16)(__float_as_uint(f) >> 16);
}

// async global->LDS, 16B per lane. LDS dest is wave-uniform base + lane*16.
__device__ __forceinline__ void gl16(const u16* g, u16* l) {
  __builtin_amdgcn_global_load_lds((const __attribute__((address_space(1))) u32*)g,
                                   (__attribute__((address_space(3))) u32*)l, 16, 0, 0);
}

// ---------------------------------------------------------------- convert x -> bf16
__global__ __launch_bounds__(256) void f32_to_bf16_k(const float* __restrict__ in,
                                                     u16* __restrict__ out, int n4) {
  int i = blockIdx.x * 256 + threadIdx.x;
  if (i >= n4) return;
  float4 v = ((const float4*)in)[i];
  ushort4 o;
  o.x = f2bf(v.x); o.y = f2bf(v.y); o.z = f2bf(v.z); o.w = f2bf(v.w);
  ((ushort4*)out)[i] = o;
}

// ---------------------------------------------------------------- transpose f32 [Rr,Cc] -> bf16 [Cc,Rr]
__global__ __launch_bounds__(256) void transpose_to_bf16(const float* __restrict__ in,
                                                         u16* __restrict__ out,
                                                         int Rr, int Cc) {
  __shared__ float tile[32][33];
  const int tx = threadIdx.x;   // 32
  const int ty = threadIdx.y;   // 8
  const int r0 = blockIdx.y << 5;
  const int c0 = blockIdx.x << 5;
#pragma unroll
  for (int i = 0; i < 4; ++i)
    tile[ty + 8 * i][tx] = in[(size_t)(r0 + ty + 8 * i) * Cc + c0 + tx];
  __syncthreads();
#pragma unroll
  for (int i = 0; i < 4; ++i)
    out[(size_t)(c0 + ty + 8 * i) * Rr + r0 + tx] = f2bf(tile[tx][ty + 8 * i]);
}

// ---------------------------------------------------------------- m97-style 128x128 MFMA GEMM
// ROUND-2 VERBATIM sync structure (known-passing). Single LDS buffer, 2 barriers/K-step.
// Only change: bijective XCD remap of the block id (pure index math; grids are %8==0).
// XCD d owns a contiguous wg chunk -> its A-panel (4 m-tile rows = 4MB) pins in its private L2.
#define SWZ4(r) (((r) & 3) ^ (((r) >> 2) & 3))
__global__ __launch_bounds__(256) void gemm128(const u16* __restrict__ A,
                                               const u16* __restrict__ Bt,
                                               void* __restrict__ Cv,
                                               int M, int N, int K, int out_bf16) {
  __shared__ __align__(16) u16 a_t[128 * 32];
  __shared__ __align__(16) u16 b_t[128 * 32];
  const int tid = threadIdx.x;
  const int wave = tid >> 6;
  const int lane = tid & 63;
  const int quad = lane >> 4;
  const int l16 = lane & 15;
  const int wm = wave >> 1;
  const int wn = wave & 1;

  // bijective XCD remap: flat -> wg so XCD (flat%8) gets contiguous wg chunk
  const int flat = blockIdx.y * gridDim.x + blockIdx.x;
  const int q8 = (gridDim.x * gridDim.y) >> 3;
  const int wg = (flat & 7) * q8 + (flat >> 3);
  const int m0 = (int)(wg / gridDim.x) << 7;
  const int n0 = (int)(wg % gridDim.x) << 7;

  // staging: inst j covers rows j*64 + (tid>>2); thread supplies global chunk (tid&3)^SWZ(row)
  const int srow = tid >> 2;
  const int scg = ((tid & 3) ^ SWZ4(srow)) << 3;
  const u16* Ag0 = A + (size_t)(m0 + srow) * K + scg;
  const u16* Ag1 = A + (size_t)(m0 + 64 + srow) * K + scg;
  const u16* Bg0 = Bt + (size_t)(n0 + srow) * K + scg;
  const u16* Bg1 = Bt + (size_t)(n0 + 64 + srow) * K + scg;
  u16* al0 = a_t + wave * 512 + lane * 8;
  u16* al1 = a_t + 2048 + wave * 512 + lane * 8;
  u16* bl0 = b_t + wave * 512 + lane * 8;
  u16* bl1 = b_t + 2048 + wave * 512 + lane * 8;

  // fragment read pointers: row = (wm*64 + mt*16 + l16); chunk = quad ^ SWZ(l16) (mt-invariant)
  const int fsw = (quad ^ SWZ4(l16)) << 3;
  const u16* afp = a_t + (wm * 64 + l16) * 32 + fsw;
  const u16* bfp = b_t + (wn * 64 + l16) * 32 + fsw;

  f32x4 acc[4][4];
#pragma unroll
  for (int i = 0; i < 4; ++i)
#pragma unroll
    for (int j = 0; j < 4; ++j) acc[i][j] = (f32x4){0.f, 0.f, 0.f, 0.f};

  for (int k0 = 0; k0 < K; k0 += 32) {
    __syncthreads();
    gl16(Ag0 + k0, al0);
    gl16(Ag1 + k0, al1);
    gl16(Bg0 + k0, bl0);
    gl16(Bg1 + k0, bl1);
    __syncthreads();
    bf16x8 af[4], bf[4];
#pragma unroll
    for (int t = 0; t < 4; ++t) {
      af[t] = *(const bf16x8*)(afp + t * 512);
      bf[t] = *(const bf16x8*)(bfp + t * 512);
    }
#pragma unroll
    for (int mt = 0; mt < 4; ++mt)
#pragma unroll
      for (int nt = 0; nt < 4; ++nt)
        acc[mt][nt] = __builtin_amdgcn_mfma_f32_16x16x32_bf16(af[mt], bf[nt], acc[mt][nt], 0, 0, 0);
  }

  // epilogue: C row = m0+wm*64+mt*16+quad*4+r, col = n0+wn*64+nt*16+l16
  if (out_bf16) {
    u16* C = (u16*)Cv;
#pragma unroll
    for (int mt = 0; mt < 4; ++mt)
#pragma unroll
      for (int r = 0; r < 4; ++r) {
        size_t base = (size_t)(m0 + wm * 64 + mt * 16 + quad * 4 + r) * N + n0 + wn * 64 + l16;
#pragma unroll
        for (int nt = 0; nt < 4; ++nt) C[base + nt * 16] = f2bf(acc[mt][nt][r]);
      }
  } else {
    float* C = (float*)Cv;
#pragma unroll
    for (int mt = 0; mt < 4; ++mt)
#pragma unroll
      for (int r = 0; r < 4; ++r) {
        size_t base = (size_t)(m0 + wm * 64 + mt * 16 + quad * 4 + r) * N + n0 + wn * 64 + l16;
#pragma unroll
        for (int nt = 0; nt < 4; ++nt) C[base + nt * 16] = acc[mt][nt][r];
      }
  }
}

// ---------------------------------------------------------------- RoPE+scale on K
// kvf: [b*s][2048] (cols 0..1023 = K heads, 1024.. = V). out kt: [b*s][1024]
__global__ __launch_bounds__(256) void rope_k_kernel(const u16* __restrict__ kvf,
                                                     u16* __restrict__ kt,
                                                     const float* __restrict__ sinT,
                                                     const float* __restrict__ cosT) {
  int idx = blockIdx.x * 256 + threadIdx.x;   // B*S*K*H = 4,194,304
  int h = idx & 127;
  int s = (idx >> 10) & 2047;
  size_t src = (size_t)(idx >> 10) * 2048 + (idx & 1023);
  float t0 = b2f(kvf[src]);
  float tp = b2f(kvf[(h < 64) ? src + 64 : src - 64]);
  float rot = (h < 64) ? -tp : tp;
  float o = (t0 * cosT[(s << 7) + h] + rot * sinT[(s << 7) + h]) * 0.08838834764831845f;
  kt[idx] = f2bf(o);
}

// ---------------------------------------------------------------- transpose V: kvf[b,t,(1024+kh*128+h)] -> [b,kh,h,t]
__global__ __launch_bounds__(256) void transpose_v(const u16* __restrict__ kvf,
                                                   u16* __restrict__ vtg) {
  __shared__ u16 tile[32][34];
  const int tx = threadIdx.x;   // 32
  const int ty = threadIdx.y;   // 8
  const int t0 = blockIdx.x << 5;
  const int h0 = blockIdx.y << 5;
  const int plane = blockIdx.z;     // b*8+kh
  const int b = plane >> 3, kh = plane & 7;
#pragma unroll
  for (int i = 0; i < 4; ++i) {
    int t = t0 + ty + 8 * i;
    tile[ty + 8 * i][tx] = kvf[(size_t)(b * 2048 + t) * 2048 + 1024 + kh * 128 + h0 + tx];
  }
  __syncthreads();
#pragma unroll
  for (int i = 0; i < 4; ++i)
    vtg[((size_t)plane * 128 + h0 + ty + 8 * i) * 2048 + t0 + tx] = tile[tx][ty + 8 * i];
}

// ---------------------------------------------------------------- MFMA flash attention (round-2 verbatim)
// 1024 blocks x 512 threads (8 waves). Block = 128 q rows of one head. Wave w: rows [qbase+16w,+16).
// K/V staged by global_load_lds into DOUBLE-BUFFERED LDS (XOR-swizzle folded into global src addr,
// LDS dest linear), 1 barrier/chunk. XCD remap pins each (b,kh) KV plane to one XCD L2.
// LDS: K dbuf 32KB + V dbuf 32KB + P 16KB = 80KiB exactly -> 2 blocks/CU = 16 waves.
__global__ __launch_bounds__(512, 4) void attn_mfma(const u16* __restrict__ qf,
                                                    const u16* __restrict__ kt,
                                                    const u16* __restrict__ vtg,
                                                    const float* __restrict__ sinT,
                                                    const float* __restrict__ cosT,
                                                    u16* __restrict__ y2) {
  __shared__ __align__(16) u16 kl[2 * 64 * 128];   // 32768 B
  __shared__ __align__(16) u16 vt[2 * 128 * 64];   // 32768 B
  __shared__ __align__(16) u16 pl[8 * 16 * 64];    // 16384 B
  const int tid = threadIdx.x;
  const int wave = tid >> 6;
  const int lane = tid & 63;
  const int quad = lane >> 4;
  const int l16 = lane & 15;
  const int sw7 = l16 & 7;

  const int flat = blockIdx.x | (blockIdx.y << 4) | (blockIdx.z << 9);  // 0..1023
  const int kh = flat & 7;
  const int j = flat >> 3;
  const int rep = j & 3;
  const int qt = 15 - ((j >> 2) & 15);
  const int b = j >> 6;
  const int head = (rep << 3) | kh;

  const int qbase = qt << 7;
  const int srow = qbase + wave * 16 + l16;
  const int row_min = qbase + wave * 16;
  const int nchunk = 2 * qt + 2;

  const size_t kbase0 = ((size_t)(b * 2048) * 8 + kh) * 128;
  const size_t vbase0 = ((size_t)(b * 8 + kh)) * 128 * 2048;

  const int krow0 = wave * 8 + (lane >> 4);
  const int krow1 = krow0 + 4;
  const u16* gK0 = kt + kbase0 + (size_t)krow0 * 1024 + (((lane & 15) ^ (krow0 & 7)) << 3);
  const u16* gK1 = kt + kbase0 + (size_t)krow1 * 1024 + (((lane & 15) ^ (krow1 & 7)) << 3);
  const int vrow0 = wave * 16 + (lane >> 3);
  const int vrow1 = vrow0 + 8;
  const u16* gV0 = vtg + vbase0 + (size_t)vrow0 * 2048 + (((lane & 7) ^ (vrow0 & 7)) << 3);
  const u16* gV1 = vtg + vbase0 + (size_t)vrow1 * 2048 + (((lane & 7) ^ (vrow1 & 7)) << 3);

  auto stage = [&](int c, int buf) {
    u16* kd = kl + buf * 8192 + wave * 1024 + lane * 8;
    u16* vd = vt + buf * 8192 + wave * 1024 + lane * 8;
    size_t ko = (size_t)c * 65536;
    size_t vo = (size_t)c * 64;
    gl16(gK0 + ko, kd);
    gl16(gK1 + ko, kd + 512);
    gl16(gV0 + vo, vd);
    gl16(gV1 + vo, vd + 512);
  };

  stage(0, 0);

  bf16x8 qfrag[4];
  {
    size_t base = ((size_t)(b * 2048 + srow)) * 4096 + (size_t)head * 128;
    float qv[32];
#pragma unroll
    for (int kk = 0; kk < 4; ++kk) {
      uint4 w = *(const uint4*)(qf + base + kk * 32 + quad * 8);
      const u16* ws = (const u16*)&w;
#pragma unroll
      for (int jj = 0; jj < 8; ++jj) qv[kk * 8 + jj] = b2f(ws[jj]);
    }
    const float* cp = cosT + (size_t)srow * 128;
    const float* sp = sinT + (size_t)srow * 128;
#pragma unroll
    for (int kk = 0; kk < 2; ++kk) {
      int hb = kk * 32 + quad * 8;
      float4 c0 = *(const float4*)(cp + hb);
      float4 c1 = *(const float4*)(cp + hb + 4);
      float4 s0 = *(const float4*)(sp + hb);
      float4 s1 = *(const float4*)(sp + hb + 4);
      float cc[8] = {c0.x, c0.y, c0.z, c0.w, c1.x, c1.y, c1.z, c1.w};
      float ss[8] = {s0.x, s0.y, s0.z, s0.w, s1.x, s1.y, s1.z, s1.w};
#pragma unroll
      for (int jj = 0; jj < 8; ++jj) {
        float a = qv[kk * 8 + jj];
        float bb = qv[(kk + 2) * 8 + jj];
        qfrag[kk][jj] = (short)f2bf(a * cc[jj] - bb * ss[jj]);
        qfrag[kk + 2][jj] = (short)f2bf(bb * cc[jj] + a * ss[jj]);
      }
    }
  }

  f32x4 o[8];
#pragma unroll
  for (int i = 0; i < 8; ++i) o[i] = (f32x4){0.f, 0.f, 0.f, 0.f};
  float run_m[4] = {-1e30f, -1e30f, -1e30f, -1e30f};
  float run_l[4] = {0.f, 0.f, 0.f, 0.f};

  u16* plw = pl + wave * 1024;
  int cur = 0;

  for (int c = 0; c < nchunk; ++c) {
    __syncthreads();
    if (c + 1 < nchunk) stage(c + 1, cur ^ 1);

    if (c * 64 <= row_min + 15) {
      const u16* kb = kl + cur * 8192;
      const u16* vb = vt + cur * 8192;

      f32x4 s[4];
      __builtin_amdgcn_s_setprio(1);
#pragma unroll
      for (int nt = 0; nt < 4; ++nt) {
        s[nt] = (f32x4){0.f, 0.f, 0.f, 0.f};
#pragma unroll
        for (int kk = 0; kk < 4; ++kk) {
          bf16x8 bf = *(const bf16x8*)(kb + (nt * 16 + l16) * 128 + (((kk * 4 + quad) ^ sw7) << 3));
          s[nt] = __builtin_amdgcn_mfma_f32_16x16x32_bf16(qfrag[kk], bf, s[nt], 0, 0, 0);
        }
      }
      __builtin_amdgcn_s_setprio(0);

      if (c * 64 + 63 > row_min) {
        int rbase = row_min + quad * 4 - c * 64;
#pragma unroll
        for (int nt = 0; nt < 4; ++nt)
#pragma unroll
          for (int rr = 0; rr < 4; ++rr)
            if (nt * 16 + l16 > rbase + rr) s[nt][rr] = -1e30f;
      }

      float p[4][4];
#pragma unroll
      for (int rr = 0; rr < 4; ++rr) {
        float cm = fmaxf(fmaxf(s[0][rr], s[1][rr]), fmaxf(s[2][rr], s[3][rr]));
#pragma unroll
        for (int off = 1; off < 16; off <<= 1) cm = fmaxf(cm, __shfl_xor(cm, off));
        float newm = fmaxf(run_m[rr], cm);
        float alpha = __expf(run_m[rr] - newm);
        float rs = 0.f;
#pragma unroll
        for (int nt = 0; nt < 4; ++nt) {
          float pv = __expf(s[nt][rr] - newm);
          p[nt][rr] = pv;
          rs += pv;
        }
#pragma unroll
        for (int off = 1; off < 16; off <<= 1) rs += __shfl_xor(rs, off);
        run_l[rr] = run_l[rr] * alpha + rs;
        run_m[rr] = newm;
#pragma unroll
        for (int ht = 0; ht < 8; ++ht) o[ht][rr] *= alpha;
      }

#pragma unroll
      for (int nt = 0; nt < 4; ++nt)
#pragma unroll
        for (int rr = 0; rr < 4; ++rr) {
          int prow = quad * 4 + rr;
          plw[prow * 64 + (((nt * 2 + (l16 >> 3)) ^ (prow & 7)) << 3) + (l16 & 7)] =
              f2bf_trunc(p[nt][rr]);
        }

      __builtin_amdgcn_s_setprio(1);
#pragma unroll
      for (int kk = 0; kk < 2; ++kk) {
        bf16x8 af = *(const bf16x8*)(plw + l16 * 64 + (((kk * 4 + quad) ^ sw7) << 3));
#pragma unroll
        for (int ht = 0; ht < 8; ++ht) {
          bf16x8 bf = *(const bf16x8*)(vb + (ht * 16 + l16) * 64 + (((kk * 4 + quad) ^ sw7) << 3));
          o[ht] = __builtin_amdgcn_mfma_f32_16x16x32_bf16(af, bf, o[ht], 0, 0, 0);
        }
      }
      __builtin_amdgcn_s_setprio(0);
    }
    cur ^= 1;
  }

  float inv_l[4];
#pragma unroll
  for (int rr = 0; rr < 4; ++rr) inv_l[rr] = 1.0f / run_l[rr];
#pragma unroll
  for (int rr = 0; rr < 4; ++rr) {
    int row = qbase + wave * 16 + quad * 4 + rr;
    size_t base = ((size_t)(b * 2048 + row)) * 4096 + (size_t)head * 128 + l16;
#pragma unroll
    for (int ht = 0; ht < 8; ++ht)
      y2[base + ht * 16] = f2bf(o[ht][rr] * inv_l[rr]);
  }
}

// ---------------------------------------------------------------- launch
extern "C" void kernel_launch(void* const* d_in, const int* in_sizes, int n_in,
                              void* d_out, int out_size, void* d_ws, size_t ws_size,
                              hipStream_t stream) {
  const float* x = (const float*)d_in[0];
  const float* wq = (const float*)d_in[1];
  const float* wk = (const float*)d_in[2];
  const float* wv = (const float*)d_in[3];
  const float* wo = (const float*)d_in[4];
  const float* sinT = (const float*)d_in[6];
  const float* cosT = (const float*)d_in[7];
  float* out = (float*)d_out;

  char* ws = (char*)d_ws;
  size_t off = 0;
  auto alloc = [&](size_t bytes) -> void* {
    void* p = ws + off;
    off += (bytes + 255) & ~(size_t)255;
    return p;
  };
  u16* xb  = (u16*)alloc(16777216ull * 2);  // x bf16 [4096,4096]
  u16* wqT = (u16*)alloc(16777216ull * 2);  // [4096(rkh),4096(d)]
  u16* wkT = (u16*)alloc(4194304ull * 2);   // [1024,4096]; together with wvT = wkvT [2048,4096]
  u16* wvT = (u16*)alloc(4194304ull * 2);   //   (contiguous: 8388608 B is 256-aligned)
  u16* woT = (u16*)alloc(16777216ull * 2);  // [4096(d),4096(rkh)]
  u16* qf  = (u16*)alloc(16777216ull * 2);  // [b,s,(r,k,h)]
  u16* kvf = (u16*)alloc(8388608ull * 2);   // [b*s,2048]: K heads | V heads
  u16* ktb = (u16*)alloc(4194304ull * 2);   // roped+scaled K, [b,s,(k,h)]
  u16* y2  = (u16*)alloc(16777216ull * 2);  // [b,s,(r,k,h)]
  (void)wvT;

  dim3 tb(32, 8);
  f32_to_bf16_k<<<dim3(16384), 256, 0, stream>>>(x, xb, 4194304);
  transpose_to_bf16<<<dim3(128, 128), tb, 0, stream>>>(wq, wqT, 4096, 4096);
  transpose_to_bf16<<<dim3(32, 128), tb, 0, stream>>>(wk, wkT, 4096, 1024);
  transpose_to_bf16<<<dim3(32, 128), tb, 0, stream>>>(wv, wvT, 4096, 1024);
  transpose_to_bf16<<<dim3(128, 128), tb, 0, stream>>>(wo, woT, 4096, 4096);

  gemm128<<<dim3(32, 32), 256, 0, stream>>>(xb, wqT, qf, 4096, 4096, 4096, 1);
  gemm128<<<dim3(16, 32), 256, 0, stream>>>(xb, wkT, kvf, 4096, 2048, 4096, 1);  // K+V fused

  rope_k_kernel<<<dim3(16384), 256, 0, stream>>>(kvf, ktb, sinT, cosT);

  u16* vtg = wkT;  // wkvT dead after KV gemm; reuse as V^T [b,kh,h,t] (8.39 MB fits exactly)
  transpose_v<<<dim3(64, 4, 16), tb, 0, stream>>>(kvf, vtg);

  attn_mfma<<<dim3(16, 32, 2), 512, 0, stream>>>(qf, ktb, vtg, sinT, cosT, y2);

  gemm128<<<dim3(32, 32), 256, 0, stream>>>(y2, woT, out, 4096, 4096, 4096, 0);
}

// Round 8
// 899.625 us; speedup vs baseline: 1.0782x; 1.0782x over previous
//
#include <hip/hip_runtime.h>

using u16 = unsigned short;
using u32 = unsigned int;

typedef short bf16x8 __attribute__((ext_vector_type(8)));
typedef float f32x4 __attribute__((ext_vector_type(4)));

__device__ __forceinline__ float b2f(u16 u) { return __uint_as_float(((u32)u) << 16); }
__device__ __forceinline__ u16 f2bf(float f) {
  u32 u = __float_as_uint(f);
  u32 r = (u + 0x7fffu + ((u >> 16) & 1u)) >> 16;
  return (u16)r;
}
__device__ __forceinline__ u16 f2bf_trunc(float f) {  // cheap truncate (P probs only)
  return (u16)(__float_as_uint(f) >> 16);
}

// async global->LDS, 16B per lane. LDS dest is wave-uniform base + lane*16.
__device__ __forceinline__ void gl16(const u16* g, u16* l) {
  __builtin_amdgcn_global_load_lds((const __attribute__((address_space(1))) u32*)g,
                                   (__attribute__((address_space(3))) u32*)l, 16, 0, 0);
}

// ---------------------------------------------------------------- convert x -> bf16
__global__ __launch_bounds__(256) void f32_to_bf16_k(const float* __restrict__ in,
                                                     u16* __restrict__ out, int n4) {
  int i = blockIdx.x * 256 + threadIdx.x;
  if (i >= n4) return;
  float4 v = ((const float4*)in)[i];
  ushort4 o;
  o.x = f2bf(v.x); o.y = f2bf(v.y); o.z = f2bf(v.z); o.w = f2bf(v.w);
  ((ushort4*)out)[i] = o;
}

// ---------------------------------------------------------------- transpose f32 [Rr,Cc] -> bf16 [Cc,Rr]
__global__ __launch_bounds__(256) void transpose_to_bf16(const float* __restrict__ in,
                                                         u16* __restrict__ out,
                                                         int Rr, int Cc) {
  __shared__ float tile[32][33];
  const int tx = threadIdx.x;   // 32
  const int ty = threadIdx.y;   // 8
  const int r0 = blockIdx.y << 5;
  const int c0 = blockIdx.x << 5;
#pragma unroll
  for (int i = 0; i < 4; ++i)
    tile[ty + 8 * i][tx] = in[(size_t)(r0 + ty + 8 * i) * Cc + c0 + tx];
  __syncthreads();
#pragma unroll
  for (int i = 0; i < 4; ++i)
    out[(size_t)(c0 + ty + 8 * i) * Rr + r0 + tx] = f2bf(tile[tx][ty + 8 * i]);
}

// ---------------------------------------------------------------- 128x128 MFMA GEMM, DOUBLE-BUFFERED
// C[M,N] = A[M,K]*Bt[N,K]^T. Block 256 (4 waves, 2x2), wave = 64x64 (4x4 16-tiles), BK=32.
// ORIGINAL block mapping (round-7 lesson: XCD remap on GEMM = 2.5x FETCH regression --
// row-major flat order already gives chip-wide A-panel locality; B is shared by all blocks).
// Experiment: double-buffered LDS, attn-proven 2-phase pattern --
//   __syncthreads() (drains prev prefetch) -> issue stage(k+1, buf^1) -> compute buf.
// One barrier per K-step; loads for tile k+1 fly under tile k's MFMA.
// LDS 2x(8KB A + 8KB B) = 32 KiB -> 5 blocks/CU.
#define SWZ4(r) (((r) & 3) ^ (((r) >> 2) & 3))
__global__ __launch_bounds__(256) void gemm128(const u16* __restrict__ A,
                                               const u16* __restrict__ Bt,
                                               void* __restrict__ Cv,
                                               int M, int N, int K, int out_bf16) {
  __shared__ __align__(16) u16 a_t[2 * 128 * 32];   // 16 KiB
  __shared__ __align__(16) u16 b_t[2 * 128 * 32];   // 16 KiB
  const int tid = threadIdx.x;
  const int wave = tid >> 6;
  const int lane = tid & 63;
  const int quad = lane >> 4;
  const int l16 = lane & 15;
  const int wm = wave >> 1;
  const int wn = wave & 1;
  const int m0 = blockIdx.y << 7;
  const int n0 = blockIdx.x << 7;

  // staging: inst j covers rows j*64 + (tid>>2); thread supplies global chunk (tid&3)^SWZ(row)
  const int srow = tid >> 2;
  const int scg = ((tid & 3) ^ SWZ4(srow)) << 3;
  const u16* Ag0 = A + (size_t)(m0 + srow) * K + scg;
  const u16* Ag1 = A + (size_t)(m0 + 64 + srow) * K + scg;
  const u16* Bg0 = Bt + (size_t)(n0 + srow) * K + scg;
  const u16* Bg1 = Bt + (size_t)(n0 + 64 + srow) * K + scg;
  u16* al = a_t + wave * 512 + lane * 8;
  u16* bl = b_t + wave * 512 + lane * 8;

  auto stage = [&](int k0, int buf) {
    const int bo = buf * 4096;
    gl16(Ag0 + k0, al + bo);
    gl16(Ag1 + k0, al + bo + 2048);
    gl16(Bg0 + k0, bl + bo);
    gl16(Bg1 + k0, bl + bo + 2048);
  };

  // fragment read pointers: row = (wm*64 + mt*16 + l16); chunk = quad ^ SWZ(l16) (mt-invariant)
  const int fsw = (quad ^ SWZ4(l16)) << 3;
  const u16* afp = a_t + (wm * 64 + l16) * 32 + fsw;
  const u16* bfp = b_t + (wn * 64 + l16) * 32 + fsw;

  f32x4 acc[4][4];
#pragma unroll
  for (int i = 0; i < 4; ++i)
#pragma unroll
    for (int j = 0; j < 4; ++j) acc[i][j] = (f32x4){0.f, 0.f, 0.f, 0.f};

  stage(0, 0);
  int cur = 0;
  for (int k0 = 0; k0 < K; k0 += 32) {
    __syncthreads();               // drains this wave's gl16s -> buf[cur] ready; prev readers done
    if (k0 + 32 < K) stage(k0 + 32, cur ^ 1);   // next tile flies under this tile's MFMA
    const int bo = cur * 4096;
    bf16x8 af[4], bf[4];
#pragma unroll
    for (int t = 0; t < 4; ++t) {
      af[t] = *(const bf16x8*)(afp + bo + t * 512);
      bf[t] = *(const bf16x8*)(bfp + bo + t * 512);
    }
    __builtin_amdgcn_s_setprio(1);
#pragma unroll
    for (int mt = 0; mt < 4; ++mt)
#pragma unroll
      for (int nt = 0; nt < 4; ++nt)
        acc[mt][nt] = __builtin_amdgcn_mfma_f32_16x16x32_bf16(af[mt], bf[nt], acc[mt][nt], 0, 0, 0);
    __builtin_amdgcn_s_setprio(0);
    cur ^= 1;
  }

  // epilogue: C row = m0+wm*64+mt*16+quad*4+r, col = n0+wn*64+nt*16+l16
  if (out_bf16) {
    u16* C = (u16*)Cv;
#pragma unroll
    for (int mt = 0; mt < 4; ++mt)
#pragma unroll
      for (int r = 0; r < 4; ++r) {
        size_t base = (size_t)(m0 + wm * 64 + mt * 16 + quad * 4 + r) * N + n0 + wn * 64 + l16;
#pragma unroll
        for (int nt = 0; nt < 4; ++nt) C[base + nt * 16] = f2bf(acc[mt][nt][r]);
      }
  } else {
    float* C = (float*)Cv;
#pragma unroll
    for (int mt = 0; mt < 4; ++mt)
#pragma unroll
      for (int r = 0; r < 4; ++r) {
        size_t base = (size_t)(m0 + wm * 64 + mt * 16 + quad * 4 + r) * N + n0 + wn * 64 + l16;
#pragma unroll
        for (int nt = 0; nt < 4; ++nt) C[base + nt * 16] = acc[mt][nt][r];
      }
  }
}

// ---------------------------------------------------------------- RoPE+scale on K
// kvf: [b*s][2048] (cols 0..1023 = K heads, 1024.. = V). out kt: [b*s][1024]
__global__ __launch_bounds__(256) void rope_k_kernel(const u16* __restrict__ kvf,
                                                     u16* __restrict__ kt,
                                                     const float* __restrict__ sinT,
                                                     const float* __restrict__ cosT) {
  int idx = blockIdx.x * 256 + threadIdx.x;   // B*S*K*H = 4,194,304
  int h = idx & 127;
  int s = (idx >> 10) & 2047;
  size_t src = (size_t)(idx >> 10) * 2048 + (idx & 1023);
  float t0 = b2f(kvf[src]);
  float tp = b2f(kvf[(h < 64) ? src + 64 : src - 64]);
  float rot = (h < 64) ? -tp : tp;
  float o = (t0 * cosT[(s << 7) + h] + rot * sinT[(s << 7) + h]) * 0.08838834764831845f;
  kt[idx] = f2bf(o);
}

// ---------------------------------------------------------------- transpose V: kvf[b,t,(1024+kh*128+h)] -> [b,kh,h,t]
__global__ __launch_bounds__(256) void transpose_v(const u16* __restrict__ kvf,
                                                   u16* __restrict__ vtg) {
  __shared__ u16 tile[32][34];
  const int tx = threadIdx.x;   // 32
  const int ty = threadIdx.y;   // 8
  const int t0 = blockIdx.x << 5;
  const int h0 = blockIdx.y << 5;
  const int plane = blockIdx.z;     // b*8+kh
  const int b = plane >> 3, kh = plane & 7;
#pragma unroll
  for (int i = 0; i < 4; ++i) {
    int t = t0 + ty + 8 * i;
    tile[ty + 8 * i][tx] = kvf[(size_t)(b * 2048 + t) * 2048 + 1024 + kh * 128 + h0 + tx];
  }
  __syncthreads();
#pragma unroll
  for (int i = 0; i < 4; ++i)
    vtg[((size_t)plane * 128 + h0 + ty + 8 * i) * 2048 + t0 + tx] = tile[tx][ty + 8 * i];
}

// ---------------------------------------------------------------- MFMA flash attention (round-2 verbatim)
// 1024 blocks x 512 threads (8 waves). Block = 128 q rows of one head. Wave w: rows [qbase+16w,+16).
// K/V staged by global_load_lds into DOUBLE-BUFFERED LDS (XOR-swizzle folded into global src addr,
// LDS dest linear), 1 barrier/chunk. XCD remap pins each (b,kh) KV plane to one XCD L2.
// LDS: K dbuf 32KB + V dbuf 32KB + P 16KB = 80KiB exactly -> 2 blocks/CU = 16 waves.
__global__ __launch_bounds__(512, 4) void attn_mfma(const u16* __restrict__ qf,
                                                    const u16* __restrict__ kt,
                                                    const u16* __restrict__ vtg,
                                                    const float* __restrict__ sinT,
                                                    const float* __restrict__ cosT,
                                                    u16* __restrict__ y2) {
  __shared__ __align__(16) u16 kl[2 * 64 * 128];   // 32768 B
  __shared__ __align__(16) u16 vt[2 * 128 * 64];   // 32768 B
  __shared__ __align__(16) u16 pl[8 * 16 * 64];    // 16384 B
  const int tid = threadIdx.x;
  const int wave = tid >> 6;
  const int lane = tid & 63;
  const int quad = lane >> 4;
  const int l16 = lane & 15;
  const int sw7 = l16 & 7;

  const int flat = blockIdx.x | (blockIdx.y << 4) | (blockIdx.z << 9);  // 0..1023
  const int kh = flat & 7;
  const int j = flat >> 3;
  const int rep = j & 3;
  const int qt = 15 - ((j >> 2) & 15);
  const int b = j >> 6;
  const int head = (rep << 3) | kh;

  const int qbase = qt << 7;
  const int srow = qbase + wave * 16 + l16;
  const int row_min = qbase + wave * 16;
  const int nchunk = 2 * qt + 2;

  const size_t kbase0 = ((size_t)(b * 2048) * 8 + kh) * 128;
  const size_t vbase0 = ((size_t)(b * 8 + kh)) * 128 * 2048;

  const int krow0 = wave * 8 + (lane >> 4);
  const int krow1 = krow0 + 4;
  const u16* gK0 = kt + kbase0 + (size_t)krow0 * 1024 + (((lane & 15) ^ (krow0 & 7)) << 3);
  const u16* gK1 = kt + kbase0 + (size_t)krow1 * 1024 + (((lane & 15) ^ (krow1 & 7)) << 3);
  const int vrow0 = wave * 16 + (lane >> 3);
  const int vrow1 = vrow0 + 8;
  const u16* gV0 = vtg + vbase0 + (size_t)vrow0 * 2048 + (((lane & 7) ^ (vrow0 & 7)) << 3);
  const u16* gV1 = vtg + vbase0 + (size_t)vrow1 * 2048 + (((lane & 7) ^ (vrow1 & 7)) << 3);

  auto stage = [&](int c, int buf) {
    u16* kd = kl + buf * 8192 + wave * 1024 + lane * 8;
    u16* vd = vt + buf * 8192 + wave * 1024 + lane * 8;
    size_t ko = (size_t)c * 65536;
    size_t vo = (size_t)c * 64;
    gl16(gK0 + ko, kd);
    gl16(gK1 + ko, kd + 512);
    gl16(gV0 + vo, vd);
    gl16(gV1 + vo, vd + 512);
  };

  stage(0, 0);

  bf16x8 qfrag[4];
  {
    size_t base = ((size_t)(b * 2048 + srow)) * 4096 + (size_t)head * 128;
    float qv[32];
#pragma unroll
    for (int kk = 0; kk < 4; ++kk) {
      uint4 w = *(const uint4*)(qf + base + kk * 32 + quad * 8);
      const u16* ws = (const u16*)&w;
#pragma unroll
      for (int jj = 0; jj < 8; ++jj) qv[kk * 8 + jj] = b2f(ws[jj]);
    }
    const float* cp = cosT + (size_t)srow * 128;
    const float* sp = sinT + (size_t)srow * 128;
#pragma unroll
    for (int kk = 0; kk < 2; ++kk) {
      int hb = kk * 32 + quad * 8;
      float4 c0 = *(const float4*)(cp + hb);
      float4 c1 = *(const float4*)(cp + hb + 4);
      float4 s0 = *(const float4*)(sp + hb);
      float4 s1 = *(const float4*)(sp + hb + 4);
      float cc[8] = {c0.x, c0.y, c0.z, c0.w, c1.x, c1.y, c1.z, c1.w};
      float ss[8] = {s0.x, s0.y, s0.z, s0.w, s1.x, s1.y, s1.z, s1.w};
#pragma unroll
      for (int jj = 0; jj < 8; ++jj) {
        float a = qv[kk * 8 + jj];
        float bb = qv[(kk + 2) * 8 + jj];
        qfrag[kk][jj] = (short)f2bf(a * cc[jj] - bb * ss[jj]);
        qfrag[kk + 2][jj] = (short)f2bf(bb * cc[jj] + a * ss[jj]);
      }
    }
  }

  f32x4 o[8];
#pragma unroll
  for (int i = 0; i < 8; ++i) o[i] = (f32x4){0.f, 0.f, 0.f, 0.f};
  float run_m[4] = {-1e30f, -1e30f, -1e30f, -1e30f};
  float run_l[4] = {0.f, 0.f, 0.f, 0.f};

  u16* plw = pl + wave * 1024;
  int cur = 0;

  for (int c = 0; c < nchunk; ++c) {
    __syncthreads();
    if (c + 1 < nchunk) stage(c + 1, cur ^ 1);

    if (c * 64 <= row_min + 15) {
      const u16* kb = kl + cur * 8192;
      const u16* vb = vt + cur * 8192;

      f32x4 s[4];
      __builtin_amdgcn_s_setprio(1);
#pragma unroll
      for (int nt = 0; nt < 4; ++nt) {
        s[nt] = (f32x4){0.f, 0.f, 0.f, 0.f};
#pragma unroll
        for (int kk = 0; kk < 4; ++kk) {
          bf16x8 bf = *(const bf16x8*)(kb + (nt * 16 + l16) * 128 + (((kk * 4 + quad) ^ sw7) << 3));
          s[nt] = __builtin_amdgcn_mfma_f32_16x16x32_bf16(qfrag[kk], bf, s[nt], 0, 0, 0);
        }
      }
      __builtin_amdgcn_s_setprio(0);

      if (c * 64 + 63 > row_min) {
        int rbase = row_min + quad * 4 - c * 64;
#pragma unroll
        for (int nt = 0; nt < 4; ++nt)
#pragma unroll
          for (int rr = 0; rr < 4; ++rr)
            if (nt * 16 + l16 > rbase + rr) s[nt][rr] = -1e30f;
      }

      float p[4][4];
#pragma unroll
      for (int rr = 0; rr < 4; ++rr) {
        float cm = fmaxf(fmaxf(s[0][rr], s[1][rr]), fmaxf(s[2][rr], s[3][rr]));
#pragma unroll
        for (int off = 1; off < 16; off <<= 1) cm = fmaxf(cm, __shfl_xor(cm, off));
        float newm = fmaxf(run_m[rr], cm);
        float alpha = __expf(run_m[rr] - newm);
        float rs = 0.f;
#pragma unroll
        for (int nt = 0; nt < 4; ++nt) {
          float pv = __expf(s[nt][rr] - newm);
          p[nt][rr] = pv;
          rs += pv;
        }
#pragma unroll
        for (int off = 1; off < 16; off <<= 1) rs += __shfl_xor(rs, off);
        run_l[rr] = run_l[rr] * alpha + rs;
        run_m[rr] = newm;
#pragma unroll
        for (int ht = 0; ht < 8; ++ht) o[ht][rr] *= alpha;
      }

#pragma unroll
      for (int nt = 0; nt < 4; ++nt)
#pragma unroll
        for (int rr = 0; rr < 4; ++rr) {
          int prow = quad * 4 + rr;
          plw[prow * 64 + (((nt * 2 + (l16 >> 3)) ^ (prow & 7)) << 3) + (l16 & 7)] =
              f2bf_trunc(p[nt][rr]);
        }

      __builtin_amdgcn_s_setprio(1);
#pragma unroll
      for (int kk = 0; kk < 2; ++kk) {
        bf16x8 af = *(const bf16x8*)(plw + l16 * 64 + (((kk * 4 + quad) ^ sw7) << 3));
#pragma unroll
        for (int ht = 0; ht < 8; ++ht) {
          bf16x8 bf = *(const bf16x8*)(vb + (ht * 16 + l16) * 64 + (((kk * 4 + quad) ^ sw7) << 3));
          o[ht] = __builtin_amdgcn_mfma_f32_16x16x32_bf16(af, bf, o[ht], 0, 0, 0);
        }
      }
      __builtin_amdgcn_s_setprio(0);
    }
    cur ^= 1;
  }

  float inv_l[4];
#pragma unroll
  for (int rr = 0; rr < 4; ++rr) inv_l[rr] = 1.0f / run_l[rr];
#pragma unroll
  for (int rr = 0; rr < 4; ++rr) {
    int row = qbase + wave * 16 + quad * 4 + rr;
    size_t base = ((size_t)(b * 2048 + row)) * 4096 + (size_t)head * 128 + l16;
#pragma unroll
    for (int ht = 0; ht < 8; ++ht)
      y2[base + ht * 16] = f2bf(o[ht][rr] * inv_l[rr]);
  }
}

// ---------------------------------------------------------------- launch
extern "C" void kernel_launch(void* const* d_in, const int* in_sizes, int n_in,
                              void* d_out, int out_size, void* d_ws, size_t ws_size,
                              hipStream_t stream) {
  const float* x = (const float*)d_in[0];
  const float* wq = (const float*)d_in[1];
  const float* wk = (const float*)d_in[2];
  const float* wv = (const float*)d_in[3];
  const float* wo = (const float*)d_in[4];
  const float* sinT = (const float*)d_in[6];
  const float* cosT = (const float*)d_in[7];
  float* out = (float*)d_out;

  char* ws = (char*)d_ws;
  size_t off = 0;
  auto alloc = [&](size_t bytes) -> void* {
    void* p = ws + off;
    off += (bytes + 255) & ~(size_t)255;
    return p;
  };
  u16* xb  = (u16*)alloc(16777216ull * 2);  // x bf16 [4096,4096]
  u16* wqT = (u16*)alloc(16777216ull * 2);  // [4096(rkh),4096(d)]
  u16* wkT = (u16*)alloc(4194304ull * 2);   // [1024,4096]; together with wvT = wkvT [2048,4096]
  u16* wvT = (u16*)alloc(4194304ull * 2);   //   (contiguous: 8388608 B is 256-aligned)
  u16* woT = (u16*)alloc(16777216ull * 2);  // [4096(d),4096(rkh)]
  u16* qf  = (u16*)alloc(16777216ull * 2);  // [b,s,(r,k,h)]
  u16* kvf = (u16*)alloc(8388608ull * 2);   // [b*s,2048]: K heads | V heads
  u16* ktb = (u16*)alloc(4194304ull * 2);   // roped+scaled K, [b,s,(k,h)]
  u16* y2  = (u16*)alloc(16777216ull * 2);  // [b,s,(r,k,h)]
  (void)wvT;

  dim3 tb(32, 8);
  f32_to_bf16_k<<<dim3(16384), 256, 0, stream>>>(x, xb, 4194304);
  transpose_to_bf16<<<dim3(128, 128), tb, 0, stream>>>(wq, wqT, 4096, 4096);
  transpose_to_bf16<<<dim3(32, 128), tb, 0, stream>>>(wk, wkT, 4096, 1024);
  transpose_to_bf16<<<dim3(32, 128), tb, 0, stream>>>(wv, wvT, 4096, 1024);
  transpose_to_bf16<<<dim3(128, 128), tb, 0, stream>>>(wo, woT, 4096, 4096);

  gemm128<<<dim3(32, 32), 256, 0, stream>>>(xb, wqT, qf, 4096, 4096, 4096, 1);
  gemm128<<<dim3(16, 32), 256, 0, stream>>>(xb, wkT, kvf, 4096, 2048, 4096, 1);  // K+V fused

  rope_k_kernel<<<dim3(16384), 256, 0, stream>>>(kvf, ktb, sinT, cosT);

  u16* vtg = wkT;  // wkvT dead after KV gemm; reuse as V^T [b,kh,h,t] (8.39 MB fits exactly)
  transpose_v<<<dim3(64, 4, 16), tb, 0, stream>>>(kvf, vtg);

  attn_mfma<<<dim3(16, 32, 2), 512, 0, stream>>>(qf, ktb, vtg, sinT, cosT, y2);

  gemm128<<<dim3(32, 32), 256, 0, stream>>>(y2, woT, out, 4096, 4096, 4096, 0);
}

// Round 9
// 750.087 us; speedup vs baseline: 1.2931x; 1.1994x over previous
//
#include <hip/hip_runtime.h>

using u16 = unsigned short;
using u32 = unsigned int;

typedef short bf16x8 __attribute__((ext_vector_type(8)));
typedef float f32x4 __attribute__((ext_vector_type(4)));

__device__ __forceinline__ float b2f(u16 u) { return __uint_as_float(((u32)u) << 16); }
__device__ __forceinline__ u16 f2bf(float f) {
  u32 u = __float_as_uint(f);
  u32 r = (u + 0x7fffu + ((u >> 16) & 1u)) >> 16;
  return (u16)r;
}
__device__ __forceinline__ u16 f2bf_trunc(float f) {  // cheap truncate (P probs only)
  return (u16)(__float_as_uint(f) >> 16);
}

// async global->LDS, 16B per lane. LDS dest is wave-uniform base + lane*16.
__device__ __forceinline__ void gl16(const u16* g, u16* l) {
  __builtin_amdgcn_global_load_lds((const __attribute__((address_space(1))) u32*)g,
                                   (__attribute__((address_space(3))) u32*)l, 16, 0, 0);
}

// raw barrier / counted vmcnt (8-phase gemm only): memory-clobbered so the compiler cannot
// reorder ds/global ops across them; no vmcnt(0) drain (that is __syncthreads' stall).
#define BARF asm volatile("s_barrier" ::: "memory")
#define VMW4 asm volatile("s_waitcnt vmcnt(4)" ::: "memory")

// ---------------------------------------------------------------- convert x -> bf16
__global__ __launch_bounds__(256) void f32_to_bf16_k(const float* __restrict__ in,
                                                     u16* __restrict__ out, int n4) {
  int i = blockIdx.x * 256 + threadIdx.x;
  if (i >= n4) return;
  float4 v = ((const float4*)in)[i];
  ushort4 o;
  o.x = f2bf(v.x); o.y = f2bf(v.y); o.z = f2bf(v.z); o.w = f2bf(v.w);
  ((ushort4*)out)[i] = o;
}

// ---------------------------------------------------------------- transpose f32 [Rr,Cc] -> bf16 [Cc,Rr]
__global__ __launch_bounds__(256) void transpose_to_bf16(const float* __restrict__ in,
                                                         u16* __restrict__ out,
                                                         int Rr, int Cc) {
  __shared__ float tile[32][33];
  const int tx = threadIdx.x;   // 32
  const int ty = threadIdx.y;   // 8
  const int r0 = blockIdx.y << 5;
  const int c0 = blockIdx.x << 5;
#pragma unroll
  for (int i = 0; i < 4; ++i)
    tile[ty + 8 * i][tx] = in[(size_t)(r0 + ty + 8 * i) * Cc + c0 + tx];
  __syncthreads();
#pragma unroll
  for (int i = 0; i < 4; ++i)
    out[(size_t)(c0 + ty + 8 * i) * Rr + r0 + tx] = f2bf(tile[tx][ty + 8 * i]);
}

// ---------------------------------------------------------------- 128x128 dbuf GEMM (KV, N=2048; round-8 proven)
#define SWZ4(r) (((r) & 3) ^ (((r) >> 2) & 3))
__global__ __launch_bounds__(256) void gemm128(const u16* __restrict__ A,
                                               const u16* __restrict__ Bt,
                                               void* __restrict__ Cv,
                                               int M, int N, int K, int out_bf16) {
  __shared__ __align__(16) u16 a_t[2 * 128 * 32];   // 16 KiB
  __shared__ __align__(16) u16 b_t[2 * 128 * 32];   // 16 KiB
  const int tid = threadIdx.x;
  const int wave = tid >> 6;
  const int lane = tid & 63;
  const int quad = lane >> 4;
  const int l16 = lane & 15;
  const int wm = wave >> 1;
  const int wn = wave & 1;
  const int m0 = blockIdx.y << 7;
  const int n0 = blockIdx.x << 7;

  const int srow = tid >> 2;
  const int scg = ((tid & 3) ^ SWZ4(srow)) << 3;
  const u16* Ag0 = A + (size_t)(m0 + srow) * K + scg;
  const u16* Ag1 = A + (size_t)(m0 + 64 + srow) * K + scg;
  const u16* Bg0 = Bt + (size_t)(n0 + srow) * K + scg;
  const u16* Bg1 = Bt + (size_t)(n0 + 64 + srow) * K + scg;
  u16* al = a_t + wave * 512 + lane * 8;
  u16* bl = b_t + wave * 512 + lane * 8;

  auto stage = [&](int k0, int buf) {
    const int bo = buf * 4096;
    gl16(Ag0 + k0, al + bo);
    gl16(Ag1 + k0, al + bo + 2048);
    gl16(Bg0 + k0, bl + bo);
    gl16(Bg1 + k0, bl + bo + 2048);
  };

  const int fsw = (quad ^ SWZ4(l16)) << 3;
  const u16* afp = a_t + (wm * 64 + l16) * 32 + fsw;
  const u16* bfp = b_t + (wn * 64 + l16) * 32 + fsw;

  f32x4 acc[4][4];
#pragma unroll
  for (int i = 0; i < 4; ++i)
#pragma unroll
    for (int j = 0; j < 4; ++j) acc[i][j] = (f32x4){0.f, 0.f, 0.f, 0.f};

  stage(0, 0);
  int cur = 0;
  for (int k0 = 0; k0 < K; k0 += 32) {
    __syncthreads();
    if (k0 + 32 < K) stage(k0 + 32, cur ^ 1);
    const int bo = cur * 4096;
    bf16x8 af[4], bf[4];
#pragma unroll
    for (int t = 0; t < 4; ++t) {
      af[t] = *(const bf16x8*)(afp + bo + t * 512);
      bf[t] = *(const bf16x8*)(bfp + bo + t * 512);
    }
    __builtin_amdgcn_s_setprio(1);
#pragma unroll
    for (int mt = 0; mt < 4; ++mt)
#pragma unroll
      for (int nt = 0; nt < 4; ++nt)
        acc[mt][nt] = __builtin_amdgcn_mfma_f32_16x16x32_bf16(af[mt], bf[nt], acc[mt][nt], 0, 0, 0);
    __builtin_amdgcn_s_setprio(0);
    cur ^= 1;
  }

  if (out_bf16) {
    u16* C = (u16*)Cv;
#pragma unroll
    for (int mt = 0; mt < 4; ++mt)
#pragma unroll
      for (int r = 0; r < 4; ++r) {
        size_t base = (size_t)(m0 + wm * 64 + mt * 16 + quad * 4 + r) * N + n0 + wn * 64 + l16;
#pragma unroll
        for (int nt = 0; nt < 4; ++nt) C[base + nt * 16] = f2bf(acc[mt][nt][r]);
      }
  } else {
    float* C = (float*)Cv;
#pragma unroll
    for (int mt = 0; mt < 4; ++mt)
#pragma unroll
      for (int r = 0; r < 4; ++r) {
        size_t base = (size_t)(m0 + wm * 64 + mt * 16 + quad * 4 + r) * N + n0 + wn * 64 + l16;
#pragma unroll
        for (int nt = 0; nt < 4; ++nt) C[base + nt * 16] = acc[mt][nt][r];
      }
  }
}

// ---------------------------------------------------------------- 256x256 8-phase MFMA GEMM (square 4096)
// m201 template. 256 blocks (1/CU), 512 thr (8 waves 2Mx4N), wave C = 128x64, BK=64.
// LDS = 2 dbuf x [256][64] x {A,B} = 128 KiB. Swizzle: 16B chunk c of row r at c^(r&7)
// (8 chunks/row -> conflict-free ds_read_b128), folded into GLOBAL src addr, LDS dest linear.
// Phase = { ds-read subtile ; stage 1 half-tile ; BARF ; 16 MFMA (setprio) ; BARF }.
// Staging schedule (WAR-safe: B halves free after ph2/ph6 trailing barrier, A after ph3/ph7;
// trailing-barrier-after-MFMA guarantees ds-reads were consumed before overwrite):
//   ph1:t1.Ah1 ph2:t1.Bh1 ph3:t2.Bh0 ph4:t2.Ah0+VMW4 ph5:t2.Ah1 ph6:t2.Bh1 ph7:t3.Bh0 ph8:t3.Ah0+VMW4
// vmcnt(4) at ph4: 12 outstanding -> 8 oldest (= t1's 4 halves) done before ph5-8 compute t1.
// vmcnt(4) at ph8: t2 done before next-iter ph1-4. Never vmcnt(0) in the loop.
// XCD chunked swizzle: with all 256 blocks CO-RESIDENT each XCD owns 2 m-rows (4MB A = its L2).
// (Round-7's XCD regression was the 1024-block sequential regime -- different working-set math.)
__global__ __launch_bounds__(512, 2) void gemm256(const u16* __restrict__ A,
                                                  const u16* __restrict__ Bt,
                                                  void* __restrict__ Cv,
                                                  int N, int K, int out_bf16) {
  __shared__ __align__(16) u16 lA[2 * 256 * 64];   // 64 KiB
  __shared__ __align__(16) u16 lB[2 * 256 * 64];   // 64 KiB
  const int tid = threadIdx.x;
  const int wave = tid >> 6, lane = tid & 63;
  const int quad = lane >> 4, l16 = lane & 15;
  const int wr = wave >> 2, wc = wave & 3;
  const int sw7 = l16 & 7;

  const int x = blockIdx.x;
  const int wg = (x & 7) * 32 + (x >> 3);   // bijective (256 % 8 == 0)
  const int tm = wg >> 4, tn = wg & 15;

  // staging: thread -> row tid>>3 (0..63), phys chunk tid&7; global chunk = (tid&7)^(row&7).
  // Each stageX covers one 128-row half: rows {srow, srow+64}, 2 x gl16.
  const int srow = tid >> 3;
  const int gch = ((tid & 7) ^ (srow & 7)) << 3;
  const u16* gA0 = A + (size_t)(tm * 256 + srow) * K + gch;          // A half 0 base
  const u16* gA1 = A + (size_t)(tm * 256 + 128 + srow) * K + gch;    // A half 1 base
  const u16* gB0 = Bt + (size_t)(tn * 256 + srow) * K + gch;
  const u16* gB1 = Bt + (size_t)(tn * 256 + 128 + srow) * K + gch;
  const int nkt = (K >> 6) - 1;

  auto stageA = [&](int kt, int h, int buf) {
    const int kc = (kt <= nkt) ? kt : 0;          // tail clamp: staged but never computed
    const u16* g = (h ? gA1 : gA0) + (size_t)kc * 64;
    u16* d = lA + buf * 16384 + h * 8192 + tid * 8;
    gl16(g, d);
    gl16(g + (size_t)K * 64, d + 4096);
  };
  auto stageB = [&](int kt, int h, int buf) {
    const int kc = (kt <= nkt) ? kt : 0;
    const u16* g = (h ? gB1 : gB0) + (size_t)kc * 64;
    u16* d = lB + buf * 16384 + h * 8192 + tid * 8;
    gl16(g, d);
    gl16(g + (size_t)K * 64, d + 4096);
  };

  // fragment read bases: row = (subtile base + l16), chunk = (kk*4+quad)^(row&7), row&7 == l16&7
  const u16* aLk0 = lA + l16 * 64 + ((quad ^ sw7) << 3);
  const u16* aLk1 = lA + l16 * 64 + (((4 + quad) ^ sw7) << 3);
  const u16* bLk0 = lB + l16 * 64 + ((quad ^ sw7) << 3);
  const u16* bLk1 = lB + l16 * 64 + (((4 + quad) ^ sw7) << 3);

  bf16x8 bA[8], bB0[4], bB1[4];
  auto loadA = [&](int buf, int rh) {   // 8 x ds_read_b128: A rows wr*128+rh*64 .. +64
    const int ro = buf * 16384 + (wr * 128 + rh * 64) * 64;
#pragma unroll
    for (int mt = 0; mt < 4; ++mt) {
      bA[mt * 2] = *(const bf16x8*)(aLk0 + ro + mt * 1024);
      bA[mt * 2 + 1] = *(const bf16x8*)(aLk1 + ro + mt * 1024);
    }
  };
  auto loadB0 = [&](int buf, int ch) {  // 4 x ds_read_b128: B rows wc*64+ch*32 .. +32
    const int ro = buf * 16384 + (wc * 64 + ch * 32) * 64;
#pragma unroll
    for (int nt = 0; nt < 2; ++nt) {
      bB0[nt * 2] = *(const bf16x8*)(bLk0 + ro + nt * 1024);
      bB0[nt * 2 + 1] = *(const bf16x8*)(bLk1 + ro + nt * 1024);
    }
  };
  auto loadB1 = [&](int buf, int ch) {
    const int ro = buf * 16384 + (wc * 64 + ch * 32) * 64;
#pragma unroll
    for (int nt = 0; nt < 2; ++nt) {
      bB1[nt * 2] = *(const bf16x8*)(bLk0 + ro + nt * 1024);
      bB1[nt * 2 + 1] = *(const bf16x8*)(bLk1 + ro + nt * 1024);
    }
  };

  f32x4 acc[2][2][4][2];                // [rh][ch][mt][nt], all indices compile-time (rule 20)
#pragma unroll
  for (int a = 0; a < 2; ++a)
#pragma unroll
    for (int b = 0; b < 2; ++b)
#pragma unroll
      for (int m = 0; m < 4; ++m)
#pragma unroll
        for (int n = 0; n < 2; ++n) acc[a][b][m][n] = (f32x4){0.f, 0.f, 0.f, 0.f};

  auto domfma = [&](f32x4(&q)[4][2], const bf16x8(&bB)[4]) {  // 16 MFMA = one C-quadrant, K=64
    __builtin_amdgcn_s_setprio(1);
#pragma unroll
    for (int mt = 0; mt < 4; ++mt)
#pragma unroll
      for (int nt = 0; nt < 2; ++nt) {
        q[mt][nt] = __builtin_amdgcn_mfma_f32_16x16x32_bf16(bA[mt * 2], bB[nt * 2], q[mt][nt], 0, 0, 0);
        q[mt][nt] = __builtin_amdgcn_mfma_f32_16x16x32_bf16(bA[mt * 2 + 1], bB[nt * 2 + 1], q[mt][nt], 0, 0, 0);
      }
    __builtin_amdgcn_s_setprio(0);
  };

  // prologue: t0 fully + t1.Bh0 + t1.Ah0 (12 loads); vmcnt(4) -> t0's 8 landed; barrier.
  stageB(0, 0, 0); stageA(0, 0, 0); stageA(0, 1, 0); stageB(0, 1, 0);
  stageB(1, 0, 1); stageA(1, 0, 1);
  VMW4;
  BARF;

  const int niter = K >> 7;   // 2 K-tiles per iteration
#pragma unroll 1
  for (int it = 0; it < niter; ++it) {
    const int t1 = 2 * it + 1, t2 = 2 * it + 2, t3 = 2 * it + 3;
    // ph1: (rh0,ch0) of tile 2it (buf0)
    loadA(0, 0); loadB0(0, 0); stageA(t1, 1, 1);
    BARF; domfma(acc[0][0], bB0); BARF;
    // ph2: (rh0,ch1)
    loadB1(0, 1); stageB(t1, 1, 1);
    BARF; domfma(acc[0][1], bB1); BARF;
    // ph3: (rh1,ch0)
    loadA(0, 1); stageB(t2, 0, 0);
    BARF; domfma(acc[1][0], bB0); BARF;
    // ph4: (rh1,ch1) -- no ds_reads
    stageA(t2, 0, 0); VMW4;
    BARF; domfma(acc[1][1], bB1); BARF;
    // ph5: (rh0,ch0) of tile 2it+1 (buf1)
    loadA(1, 0); loadB0(1, 0); stageA(t2, 1, 0);
    BARF; domfma(acc[0][0], bB0); BARF;
    // ph6
    loadB1(1, 1); stageB(t2, 1, 0);
    BARF; domfma(acc[0][1], bB1); BARF;
    // ph7
    loadA(1, 1); stageB(t3, 0, 1);
    BARF; domfma(acc[1][0], bB0); BARF;
    // ph8
    stageA(t3, 0, 1); VMW4;
    BARF; domfma(acc[1][1], bB1); BARF;
  }

  // epilogue: row = tm*256+wr*128+rh*64+mt*16+quad*4+r; col = tn*256+wc*64+ch*32+nt*16+l16
  if (out_bf16) {
    u16* C = (u16*)Cv;
#pragma unroll
    for (int rh = 0; rh < 2; ++rh)
#pragma unroll
      for (int mt = 0; mt < 4; ++mt)
#pragma unroll
        for (int r = 0; r < 4; ++r) {
          size_t base = (size_t)(tm * 256 + wr * 128 + rh * 64 + mt * 16 + quad * 4 + r) * N +
                        tn * 256 + wc * 64 + l16;
#pragma unroll
          for (int ch = 0; ch < 2; ++ch)
#pragma unroll
            for (int nt = 0; nt < 2; ++nt)
              C[base + ch * 32 + nt * 16] = f2bf(acc[rh][ch][mt][nt][r]);
        }
  } else {
    float* C = (float*)Cv;
#pragma unroll
    for (int rh = 0; rh < 2; ++rh)
#pragma unroll
      for (int mt = 0; mt < 4; ++mt)
#pragma unroll
        for (int r = 0; r < 4; ++r) {
          size_t base = (size_t)(tm * 256 + wr * 128 + rh * 64 + mt * 16 + quad * 4 + r) * N +
                        tn * 256 + wc * 64 + l16;
#pragma unroll
          for (int ch = 0; ch < 2; ++ch)
#pragma unroll
            for (int nt = 0; nt < 2; ++nt)
              C[base + ch * 32 + nt * 16] = acc[rh][ch][mt][nt][r];
        }
  }
}

// ---------------------------------------------------------------- RoPE+scale on K
__global__ __launch_bounds__(256) void rope_k_kernel(const u16* __restrict__ kvf,
                                                     u16* __restrict__ kt,
                                                     const float* __restrict__ sinT,
                                                     const float* __restrict__ cosT) {
  int idx = blockIdx.x * 256 + threadIdx.x;   // B*S*K*H = 4,194,304
  int h = idx & 127;
  int s = (idx >> 10) & 2047;
  size_t src = (size_t)(idx >> 10) * 2048 + (idx & 1023);
  float t0 = b2f(kvf[src]);
  float tp = b2f(kvf[(h < 64) ? src + 64 : src - 64]);
  float rot = (h < 64) ? -tp : tp;
  float o = (t0 * cosT[(s << 7) + h] + rot * sinT[(s << 7) + h]) * 0.08838834764831845f;
  kt[idx] = f2bf(o);
}

// ---------------------------------------------------------------- transpose V: kvf[b,t,(1024+kh*128+h)] -> [b,kh,h,t]
__global__ __launch_bounds__(256) void transpose_v(const u16* __restrict__ kvf,
                                                   u16* __restrict__ vtg) {
  __shared__ u16 tile[32][34];
  const int tx = threadIdx.x;   // 32
  const int ty = threadIdx.y;   // 8
  const int t0 = blockIdx.x << 5;
  const int h0 = blockIdx.y << 5;
  const int plane = blockIdx.z;     // b*8+kh
  const int b = plane >> 3, kh = plane & 7;
#pragma unroll
  for (int i = 0; i < 4; ++i) {
    int t = t0 + ty + 8 * i;
    tile[ty + 8 * i][tx] = kvf[(size_t)(b * 2048 + t) * 2048 + 1024 + kh * 128 + h0 + tx];
  }
  __syncthreads();
#pragma unroll
  for (int i = 0; i < 4; ++i)
    vtg[((size_t)plane * 128 + h0 + ty + 8 * i) * 2048 + t0 + tx] = tile[tx][ty + 8 * i];
}

// ---------------------------------------------------------------- MFMA flash attention (round-2/8 proven)
__global__ __launch_bounds__(512, 4) void attn_mfma(const u16* __restrict__ qf,
                                                    const u16* __restrict__ kt,
                                                    const u16* __restrict__ vtg,
                                                    const float* __restrict__ sinT,
                                                    const float* __restrict__ cosT,
                                                    u16* __restrict__ y2) {
  __shared__ __align__(16) u16 kl[2 * 64 * 128];   // 32768 B
  __shared__ __align__(16) u16 vt[2 * 128 * 64];   // 32768 B
  __shared__ __align__(16) u16 pl[8 * 16 * 64];    // 16384 B
  const int tid = threadIdx.x;
  const int wave = tid >> 6;
  const int lane = tid & 63;
  const int quad = lane >> 4;
  const int l16 = lane & 15;
  const int sw7 = l16 & 7;

  const int flat = blockIdx.x | (blockIdx.y << 4) | (blockIdx.z << 9);  // 0..1023
  const int kh = flat & 7;
  const int j = flat >> 3;
  const int rep = j & 3;
  const int qt = 15 - ((j >> 2) & 15);
  const int b = j >> 6;
  const int head = (rep << 3) | kh;

  const int qbase = qt << 7;
  const int srow = qbase + wave * 16 + l16;
  const int row_min = qbase + wave * 16;
  const int nchunk = 2 * qt + 2;

  const size_t kbase0 = ((size_t)(b * 2048) * 8 + kh) * 128;
  const size_t vbase0 = ((size_t)(b * 8 + kh)) * 128 * 2048;

  const int krow0 = wave * 8 + (lane >> 4);
  const int krow1 = krow0 + 4;
  const u16* gK0 = kt + kbase0 + (size_t)krow0 * 1024 + (((lane & 15) ^ (krow0 & 7)) << 3);
  const u16* gK1 = kt + kbase0 + (size_t)krow1 * 1024 + (((lane & 15) ^ (krow1 & 7)) << 3);
  const int vrow0 = wave * 16 + (lane >> 3);
  const int vrow1 = vrow0 + 8;
  const u16* gV0 = vtg + vbase0 + (size_t)vrow0 * 2048 + (((lane & 7) ^ (vrow0 & 7)) << 3);
  const u16* gV1 = vtg + vbase0 + (size_t)vrow1 * 2048 + (((lane & 7) ^ (vrow1 & 7)) << 3);

  auto stage = [&](int c, int buf) {
    u16* kd = kl + buf * 8192 + wave * 1024 + lane * 8;
    u16* vd = vt + buf * 8192 + wave * 1024 + lane * 8;
    size_t ko = (size_t)c * 65536;
    size_t vo = (size_t)c * 64;
    gl16(gK0 + ko, kd);
    gl16(gK1 + ko, kd + 512);
    gl16(gV0 + vo, vd);
    gl16(gV1 + vo, vd + 512);
  };

  stage(0, 0);

  bf16x8 qfrag[4];
  {
    size_t base = ((size_t)(b * 2048 + srow)) * 4096 + (size_t)head * 128;
    float qv[32];
#pragma unroll
    for (int kk = 0; kk < 4; ++kk) {
      uint4 w = *(const uint4*)(qf + base + kk * 32 + quad * 8);
      const u16* ws = (const u16*)&w;
#pragma unroll
      for (int jj = 0; jj < 8; ++jj) qv[kk * 8 + jj] = b2f(ws[jj]);
    }
    const float* cp = cosT + (size_t)srow * 128;
    const float* sp = sinT + (size_t)srow * 128;
#pragma unroll
    for (int kk = 0; kk < 2; ++kk) {
      int hb = kk * 32 + quad * 8;
      float4 c0 = *(const float4*)(cp + hb);
      float4 c1 = *(const float4*)(cp + hb + 4);
      float4 s0 = *(const float4*)(sp + hb);
      float4 s1 = *(const float4*)(sp + hb + 4);
      float cc[8] = {c0.x, c0.y, c0.z, c0.w, c1.x, c1.y, c1.z, c1.w};
      float ss[8] = {s0.x, s0.y, s0.z, s0.w, s1.x, s1.y, s1.z, s1.w};
#pragma unroll
      for (int jj = 0; jj < 8; ++jj) {
        float a = qv[kk * 8 + jj];
        float bb = qv[(kk + 2) * 8 + jj];
        qfrag[kk][jj] = (short)f2bf(a * cc[jj] - bb * ss[jj]);
        qfrag[kk + 2][jj] = (short)f2bf(bb * cc[jj] + a * ss[jj]);
      }
    }
  }

  f32x4 o[8];
#pragma unroll
  for (int i = 0; i < 8; ++i) o[i] = (f32x4){0.f, 0.f, 0.f, 0.f};
  float run_m[4] = {-1e30f, -1e30f, -1e30f, -1e30f};
  float run_l[4] = {0.f, 0.f, 0.f, 0.f};

  u16* plw = pl + wave * 1024;
  int cur = 0;

  for (int c = 0; c < nchunk; ++c) {
    __syncthreads();
    if (c + 1 < nchunk) stage(c + 1, cur ^ 1);

    if (c * 64 <= row_min + 15) {
      const u16* kb = kl + cur * 8192;
      const u16* vb = vt + cur * 8192;

      f32x4 s[4];
      __builtin_amdgcn_s_setprio(1);
#pragma unroll
      for (int nt = 0; nt < 4; ++nt) {
        s[nt] = (f32x4){0.f, 0.f, 0.f, 0.f};
#pragma unroll
        for (int kk = 0; kk < 4; ++kk) {
          bf16x8 bf = *(const bf16x8*)(kb + (nt * 16 + l16) * 128 + (((kk * 4 + quad) ^ sw7) << 3));
          s[nt] = __builtin_amdgcn_mfma_f32_16x16x32_bf16(qfrag[kk], bf, s[nt], 0, 0, 0);
        }
      }
      __builtin_amdgcn_s_setprio(0);

      if (c * 64 + 63 > row_min) {
        int rbase = row_min + quad * 4 - c * 64;
#pragma unroll
        for (int nt = 0; nt < 4; ++nt)
#pragma unroll
          for (int rr = 0; rr < 4; ++rr)
            if (nt * 16 + l16 > rbase + rr) s[nt][rr] = -1e30f;
      }

      float p[4][4];
#pragma unroll
      for (int rr = 0; rr < 4; ++rr) {
        float cm = fmaxf(fmaxf(s[0][rr], s[1][rr]), fmaxf(s[2][rr], s[3][rr]));
#pragma unroll
        for (int off = 1; off < 16; off <<= 1) cm = fmaxf(cm, __shfl_xor(cm, off));
        float newm = fmaxf(run_m[rr], cm);
        float alpha = __expf(run_m[rr] - newm);
        float rs = 0.f;
#pragma unroll
        for (int nt = 0; nt < 4; ++nt) {
          float pv = __expf(s[nt][rr] - newm);
          p[nt][rr] = pv;
          rs += pv;
        }
#pragma unroll
        for (int off = 1; off < 16; off <<= 1) rs += __shfl_xor(rs, off);
        run_l[rr] = run_l[rr] * alpha + rs;
        run_m[rr] = newm;
#pragma unroll
        for (int ht = 0; ht < 8; ++ht) o[ht][rr] *= alpha;
      }

#pragma unroll
      for (int nt = 0; nt < 4; ++nt)
#pragma unroll
        for (int rr = 0; rr < 4; ++rr) {
          int prow = quad * 4 + rr;
          plw[prow * 64 + (((nt * 2 + (l16 >> 3)) ^ (prow & 7)) << 3) + (l16 & 7)] =
              f2bf_trunc(p[nt][rr]);
        }

      __builtin_amdgcn_s_setprio(1);
#pragma unroll
      for (int kk = 0; kk < 2; ++kk) {
        bf16x8 af = *(const bf16x8*)(plw + l16 * 64 + (((kk * 4 + quad) ^ sw7) << 3));
#pragma unroll
        for (int ht = 0; ht < 8; ++ht) {
          bf16x8 bf = *(const bf16x8*)(vb + (ht * 16 + l16) * 64 + (((kk * 4 + quad) ^ sw7) << 3));
          o[ht] = __builtin_amdgcn_mfma_f32_16x16x32_bf16(af, bf, o[ht], 0, 0, 0);
        }
      }
      __builtin_amdgcn_s_setprio(0);
    }
    cur ^= 1;
  }

  float inv_l[4];
#pragma unroll
  for (int rr = 0; rr < 4; ++rr) inv_l[rr] = 1.0f / run_l[rr];
#pragma unroll
  for (int rr = 0; rr < 4; ++rr) {
    int row = qbase + wave * 16 + quad * 4 + rr;
    size_t base = ((size_t)(b * 2048 + row)) * 4096 + (size_t)head * 128 + l16;
#pragma unroll
    for (int ht = 0; ht < 8; ++ht)
      y2[base + ht * 16] = f2bf(o[ht][rr] * inv_l[rr]);
  }
}

// ---------------------------------------------------------------- launch
extern "C" void kernel_launch(void* const* d_in, const int* in_sizes, int n_in,
                              void* d_out, int out_size, void* d_ws, size_t ws_size,
                              hipStream_t stream) {
  const float* x = (const float*)d_in[0];
  const float* wq = (const float*)d_in[1];
  const float* wk = (const float*)d_in[2];
  const float* wv = (const float*)d_in[3];
  const float* wo = (const float*)d_in[4];
  const float* sinT = (const float*)d_in[6];
  const float* cosT = (const float*)d_in[7];
  float* out = (float*)d_out;

  char* ws = (char*)d_ws;
  size_t off = 0;
  auto alloc = [&](size_t bytes) -> void* {
    void* p = ws + off;
    off += (bytes + 255) & ~(size_t)255;
    return p;
  };
  u16* xb  = (u16*)alloc(16777216ull * 2);  // x bf16 [4096,4096]
  u16* wqT = (u16*)alloc(16777216ull * 2);  // [4096(rkh),4096(d)]
  u16* wkT = (u16*)alloc(4194304ull * 2);   // [1024,4096]; together with wvT = wkvT [2048,4096]
  u16* wvT = (u16*)alloc(4194304ull * 2);   //   (contiguous: 8388608 B is 256-aligned)
  u16* woT = (u16*)alloc(16777216ull * 2);  // [4096(d),4096(rkh)]
  u16* qf  = (u16*)alloc(16777216ull * 2);  // [b,s,(r,k,h)]
  u16* kvf = (u16*)alloc(8388608ull * 2);   // [b*s,2048]: K heads | V heads
  u16* ktb = (u16*)alloc(4194304ull * 2);   // roped+scaled K, [b,s,(k,h)]
  u16* y2  = (u16*)alloc(16777216ull * 2);  // [b,s,(r,k,h)]
  (void)wvT;

  dim3 tb(32, 8);
  f32_to_bf16_k<<<dim3(16384), 256, 0, stream>>>(x, xb, 4194304);
  transpose_to_bf16<<<dim3(128, 128), tb, 0, stream>>>(wq, wqT, 4096, 4096);
  transpose_to_bf16<<<dim3(32, 128), tb, 0, stream>>>(wk, wkT, 4096, 1024);
  transpose_to_bf16<<<dim3(32, 128), tb, 0, stream>>>(wv, wvT, 4096, 1024);
  transpose_to_bf16<<<dim3(128, 128), tb, 0, stream>>>(wo, woT, 4096, 4096);

  gemm256<<<dim3(256), 512, 0, stream>>>(xb, wqT, qf, 4096, 4096, 1);
  gemm128<<<dim3(16, 32), 256, 0, stream>>>(xb, wkT, kvf, 4096, 2048, 4096, 1);  // K+V fused

  rope_k_kernel<<<dim3(16384), 256, 0, stream>>>(kvf, ktb, sinT, cosT);

  u16* vtg = wkT;  // wkvT dead after KV gemm; reuse as V^T [b,kh,h,t] (8.39 MB fits exactly)
  transpose_v<<<dim3(64, 4, 16), tb, 0, stream>>>(kvf, vtg);

  attn_mfma<<<dim3(16, 32, 2), 512, 0, stream>>>(qf, ktb, vtg, sinT, cosT, y2);

  gemm256<<<dim3(256), 512, 0, stream>>>(y2, woT, out, 4096, 4096, 0);
}